// Round 7
// baseline (267.100 us; speedup 1.0000x reference)
//
#include <hip/hip_runtime.h>
#include <hip/hip_bf16.h>

#define BATCH 128
#define TLEN  65536
#define EDIM  512
#define SMAX  512

typedef __attribute__((ext_vector_type(8))) short   bf16x8;
typedef __attribute__((ext_vector_type(4))) float   floatx4;
typedef __attribute__((ext_vector_type(8))) ushort  ushort8;

__device__ __forceinline__ ushort f2bf(float f) {
  __hip_bfloat16 h = __float2bfloat16(f);  // RNE
  return *reinterpret_cast<ushort*>(&h);
}

__device__ __forceinline__ void cvt16(ushort* dst, float4 a, float4 b,
                                      float4 c, float4 d) {
  ushort8 p0, p1;
  p0[0]=f2bf(a.x); p0[1]=f2bf(a.y); p0[2]=f2bf(a.z); p0[3]=f2bf(a.w);
  p0[4]=f2bf(b.x); p0[5]=f2bf(b.y); p0[6]=f2bf(b.z); p0[7]=f2bf(b.w);
  p1[0]=f2bf(c.x); p1[1]=f2bf(c.y); p1[2]=f2bf(c.z); p1[3]=f2bf(c.w);
  p1[4]=f2bf(d.x); p1[5]=f2bf(d.y); p1[6]=f2bf(d.z); p1[7]=f2bf(d.w);
  *(ushort8*)dst = p0; *(ushort8*)(dst + 8) = p1;
}

__device__ __forceinline__ void gl_lds16(const ushort* g, ushort* l) {
  __builtin_amdgcn_global_load_lds(
      (const __attribute__((address_space(1))) void*)g,
      (__attribute__((address_space(3))) void*)l, 16, 0, 0);
}

// ---------------------------------------------------------------------------
// mask popcount stage A: part[b*8+c] = popcount of 8192-int chunk c of row b
// ---------------------------------------------------------------------------
__global__ __launch_bounds__(256) void mask_partial_kernel(
    const int* __restrict__ mask, int* __restrict__ part) {
  const int b = blockIdx.x, c = blockIdx.y, t = threadIdx.x;
  const int4* row = (const int4*)(mask + (size_t)b * TLEN + (size_t)c * 8192);
  int s = 0;
  #pragma unroll
  for (int i = 0; i < 8; ++i) {
    int4 v = row[t + i * 256];
    s += (v.x != 0) + (v.y != 0) + (v.z != 0) + (v.w != 0);
  }
  #pragma unroll
  for (int off = 32; off > 0; off >>= 1) s += __shfl_down(s, off);
  __shared__ int partial[4];
  if ((t & 63) == 0) partial[t >> 6] = s;
  __syncthreads();
  if (t == 0)
    part[b * 8 + c] = partial[0] + partial[1] + partial[2] + partial[3];
}

// ---------------------------------------------------------------------------
// mask stage B: n_valid[b] + padding_mask output
// ---------------------------------------------------------------------------
__global__ __launch_bounds__(256) void mask_final_kernel(
    const int* __restrict__ part, const int* __restrict__ branch_idx,
    int* __restrict__ n_valid, float* __restrict__ out_mask) {
  const int b = blockIdx.x, t = threadIdx.x;
  __shared__ int nv_sh;
  if (t == 0) {
    int len = 0;
    #pragma unroll
    for (int i = 0; i < 8; ++i) len += part[b * 8 + i];
    int w = 128 << branch_idx[b];
    int nv = len / w;
    n_valid[b] = nv;
    nv_sh = nv;
  }
  __syncthreads();
  const int nv = nv_sh;
  out_mask[(size_t)b * SMAX + t]       = (t < nv)       ? 1.0f : 0.0f;
  out_mask[(size_t)b * SMAX + 256 + t] = (256 + t < nv) ? 1.0f : 0.0f;
}

// ---------------------------------------------------------------------------
// f32 -> bf16 pre-convert of signal + weights into ws (flat concat).
// ---------------------------------------------------------------------------
#define SIGN  (BATCH * TLEN)        // 8,388,608
#define W0N   (EDIM * 128)
#define W1N   (EDIM * 256)
#define W2N   (EDIM * 512)
#define CVT_TOTAL (SIGN + W0N + W1N + W2N)   // 8,847,360 = 4096*2160

__global__ __launch_bounds__(256) void cvt_kernel(
    const float* __restrict__ sig, const float* __restrict__ W0,
    const float* __restrict__ W1, const float* __restrict__ W2,
    ushort* __restrict__ dst) {
  const size_t i = ((size_t)blockIdx.x * 256 + threadIdx.x) * 16;
  const float* src;
  if (i < SIGN)                  src = sig + i;
  else if (i < SIGN + W0N)       src = W0 + (i - SIGN);
  else if (i < SIGN + W0N + W1N) src = W1 + (i - SIGN - W0N);
  else                           src = W2 + (i - SIGN - W0N - W1N);
  const float4* s4 = (const float4*)src;
  cvt16(dst + i, s4[0], s4[1], s4[2], s4[3]);
}

// ---------------------------------------------------------------------------
// Main MFMA GEMM (bf16 inputs from ws, global_load_lds staging, dbuf LDS).
// 128x128 tile, 4 waves (2x2 of 64x64), BK=32, 16x16x32 bf16 MFMA.
// Grid is 1-D, XCD-swizzled: L = group*32 + et*8 + slot, so the 4 e-tile
// blocks sharing one A-strip have identical L%8 -> same XCD -> the strip is
// fetched into that XCD's L2 once, and k-loop DMA hits L2 (~200cy not ~900).
// __launch_bounds__(256,5): 5 blocks/CU (32 KB LDS each) for stall overlap.
// ---------------------------------------------------------------------------
template <int W>
__device__ __forceinline__ void gemm_mfma_body(
    const ushort* __restrict__ sigb, const ushort* __restrict__ Wp,
    const float* __restrict__ bp, float* __restrict__ outb,
    int nv, int s0, int e0, int t, ushort* Abuf, ushort* Bbuf) {
  constexpr int ITERS = W / 32;
  const int wave = t >> 6, lane = t & 63;
  const int lane16 = lane & 15, quad = lane >> 4;
  const int ws_ = (wave >> 1) * 64, we_ = (wave & 1) * 64;

  // staging: thread t covers flat 16B-chunks t and t+256 of each matrix;
  // chunk c -> row c>>2, swizzled k-chunk (c&3)^(row&3)
  const int c0 = t,        r0 = c0 >> 2, kc0 = (c0 & 3) ^ (r0 & 3);
  const int c1 = t + 256,  r1 = c1 >> 2, kc1 = (c1 & 3) ^ (r1 & 3);
  const ushort* ag0 = sigb + (size_t)(s0 + r0) * W + kc0 * 8;
  const ushort* ag1 = sigb + (size_t)(s0 + r1) * W + kc1 * 8;
  const ushort* bg0 = Wp + (size_t)(e0 + r0) * W + kc0 * 8;
  const ushort* bg1 = Wp + (size_t)(e0 + r1) * W + kc1 * 8;
  // wave-uniform LDS dest bases (HW adds lane*16B)
  ushort* al0 = Abuf + wave * 512;
  ushort* al1 = Abuf + 2048 + wave * 512;
  ushort* bl0 = Bbuf + wave * 512;
  ushort* bl1 = Bbuf + 2048 + wave * 512;

  floatx4 acc[4][4];
  #pragma unroll
  for (int i = 0; i < 4; ++i)
    #pragma unroll
    for (int j = 0; j < 4; ++j) acc[i][j] = (floatx4)(0.f);

  // stage 0 into buffer 0
  gl_lds16(ag0, al0); gl_lds16(ag1, al1);
  gl_lds16(bg0, bl0); gl_lds16(bg1, bl1);
  __syncthreads();

  const int slotq = (quad ^ (lane16 & 3)) * 8;  // swizzled read pos, const/lane

  #pragma unroll
  for (int k = 0; k < ITERS; ++k) {
    if (k + 1 < ITERS) {  // prefetch next stage into the other buffer
      const size_t ko = (size_t)(k + 1) * 32;
      const int p = ((k + 1) & 1) * 4096;
      gl_lds16(ag0 + ko, al0 + p); gl_lds16(ag1 + ko, al1 + p);
      gl_lds16(bg0 + ko, bl0 + p); gl_lds16(bg1 + ko, bl1 + p);
    }
    const ushort* A = Abuf + (k & 1) * 4096;
    const ushort* B = Bbuf + (k & 1) * 4096;
    bf16x8 af[4], bfr[4];
    #pragma unroll
    for (int i = 0; i < 4; ++i)
      af[i] = *(const bf16x8*)&A[(ws_ + i * 16 + lane16) * 32 + slotq];
    #pragma unroll
    for (int j = 0; j < 4; ++j)
      bfr[j] = *(const bf16x8*)&B[(we_ + j * 16 + lane16) * 32 + slotq];
    #pragma unroll
    for (int i = 0; i < 4; ++i)
      #pragma unroll
      for (int j = 0; j < 4; ++j)
        acc[i][j] = __builtin_amdgcn_mfma_f32_16x16x32_bf16(af[i], bfr[j], acc[i][j], 0, 0, 0);
    __syncthreads();
  }

  // epilogue: bias + row masking (exact zeros for rows >= nv)
  float bval[4];
  #pragma unroll
  for (int j = 0; j < 4; ++j) bval[j] = bp[e0 + we_ + j * 16 + lane16];
  #pragma unroll
  for (int i = 0; i < 4; ++i) {
    #pragma unroll
    for (int rr = 0; rr < 4; ++rr) {
      const int s_row = s0 + ws_ + i * 16 + quad * 4 + rr;
      const bool valid = s_row < nv;
      float* op = outb + (size_t)s_row * EDIM + e0 + we_ + lane16;
      #pragma unroll
      for (int j = 0; j < 4; ++j)
        op[j * 16] = valid ? (acc[i][j][rr] + bval[j]) : 0.f;
    }
  }
}

__global__ __launch_bounds__(256, 5) void gemm_bf_kernel(
    const ushort* __restrict__ sigbf, const int* __restrict__ branch_idx,
    const int* __restrict__ n_valid_arr,
    const ushort* __restrict__ W0b, const float* __restrict__ bias0,
    const ushort* __restrict__ W1b, const float* __restrict__ bias1,
    const ushort* __restrict__ W2b, const float* __restrict__ bias2,
    float* __restrict__ out) {
  // XCD-aware decode: slot(3b) | et(2b) | group(6b)
  const int L = blockIdx.x;
  const int slot = L & 7;
  const int et = (L >> 3) & 3;
  const int p = (L >> 5) * 8 + slot;   // 0..511
  const int st = p & 3;
  const int b = p >> 2;
  const int t = threadIdx.x;
  const int s0 = st * 128, e0 = et * 128;
  const int bi = branch_idx[b];
  const int S_b = 512 >> bi;
  float* outb = out + (size_t)b * SMAX * EDIM;

  if (s0 >= S_b) {  // pure pad tile: zero-fill (harness poisons d_out)
    const float4 z = make_float4(0.f, 0.f, 0.f, 0.f);
    #pragma unroll
    for (int i = 0; i < 16; ++i) {
      int idx = t + i * 256;
      int r = idx >> 5, c = idx & 31;
      *(float4*)(outb + (size_t)(s0 + r) * EDIM + e0 + c * 4) = z;
    }
    return;
  }

  __shared__ __align__(16) ushort Abuf[2 * 4096];  // 16 KB
  __shared__ __align__(16) ushort Bbuf[2 * 4096];  // 16 KB
  const int nv = n_valid_arr[b];
  const ushort* sigb = sigbf + (size_t)b * TLEN;
  switch (bi) {
    case 0:  gemm_mfma_body<128>(sigb, W0b, bias0, outb, nv, s0, e0, t, Abuf, Bbuf); break;
    case 1:  gemm_mfma_body<256>(sigb, W1b, bias1, outb, nv, s0, e0, t, Abuf, Bbuf); break;
    default: gemm_mfma_body<512>(sigb, W2b, bias2, outb, nv, s0, e0, t, Abuf, Bbuf); break;
  }
}

// ---------------------------------------------------------------------------
// Fallback GEMM (inline f32->bf16 staging) if ws is too small.
// ---------------------------------------------------------------------------
#define LDS_STRIDE 40
#define BUFSZ (128 * LDS_STRIDE)

template <int W>
__device__ __forceinline__ void gemm_fb_body(
    const float* __restrict__ sigb, const float* __restrict__ Wp,
    const float* __restrict__ bp, float* __restrict__ outb,
    int nv, int s0, int e0, int t, ushort* Ab, ushort* Bb) {
  constexpr int ITERS = W / 32;
  const int wave = t >> 6, lane = t & 63;
  const int lane16 = lane & 15, quad = lane >> 4;
  const int ws_ = (wave >> 1) * 64, we_ = (wave & 1) * 64;
  const int r = t >> 1, h = t & 1;
  const float* asrc = sigb + (size_t)(s0 + r) * W + h * 16;
  const float* bsrc = Wp + (size_t)(e0 + r) * W + h * 16;
  {
    const float4* a4 = (const float4*)asrc;
    const float4* b4 = (const float4*)bsrc;
    cvt16(Ab + r * LDS_STRIDE + h * 16, a4[0], a4[1], a4[2], a4[3]);
    cvt16(Bb + r * LDS_STRIDE + h * 16, b4[0], b4[1], b4[2], b4[3]);
  }
  __syncthreads();
  floatx4 acc[4][4];
  #pragma unroll
  for (int i = 0; i < 4; ++i)
    #pragma unroll
    for (int j = 0; j < 4; ++j) acc[i][j] = (floatx4)(0.f);
  #pragma unroll
  for (int k = 0; k < ITERS; ++k) {
    const ushort* curA = Ab + (k & 1) * BUFSZ;
    const ushort* curB = Bb + (k & 1) * BUFSZ;
    float4 av0, av1, av2, av3, bv0, bv1, bv2, bv3;
    if (k + 1 < ITERS) {
      const float4* a4 = (const float4*)(asrc + (k + 1) * 32);
      const float4* b4 = (const float4*)(bsrc + (k + 1) * 32);
      av0 = a4[0]; av1 = a4[1]; av2 = a4[2]; av3 = a4[3];
      bv0 = b4[0]; bv1 = b4[1]; bv2 = b4[2]; bv3 = b4[3];
    }
    bf16x8 af[4], bfr[4];
    #pragma unroll
    for (int i = 0; i < 4; ++i)
      af[i] = *(const bf16x8*)&curA[(ws_ + i * 16 + lane16) * LDS_STRIDE + quad * 8];
    #pragma unroll
    for (int j = 0; j < 4; ++j)
      bfr[j] = *(const bf16x8*)&curB[(we_ + j * 16 + lane16) * LDS_STRIDE + quad * 8];
    #pragma unroll
    for (int i = 0; i < 4; ++i)
      #pragma unroll
      for (int j = 0; j < 4; ++j)
        acc[i][j] = __builtin_amdgcn_mfma_f32_16x16x32_bf16(af[i], bfr[j], acc[i][j], 0, 0, 0);
    if (k + 1 < ITERS) {
      cvt16(Ab + ((k + 1) & 1) * BUFSZ + r * LDS_STRIDE + h * 16, av0, av1, av2, av3);
      cvt16(Bb + ((k + 1) & 1) * BUFSZ + r * LDS_STRIDE + h * 16, bv0, bv1, bv2, bv3);
      __syncthreads();
    }
  }
  float bval[4];
  #pragma unroll
  for (int j = 0; j < 4; ++j) bval[j] = bp[e0 + we_ + j * 16 + lane16];
  #pragma unroll
  for (int i = 0; i < 4; ++i) {
    #pragma unroll
    for (int rr = 0; rr < 4; ++rr) {
      const int s_row = s0 + ws_ + i * 16 + quad * 4 + rr;
      const bool valid = s_row < nv;
      float* op = outb + (size_t)s_row * EDIM + e0 + we_ + lane16;
      #pragma unroll
      for (int j = 0; j < 4; ++j)
        op[j * 16] = valid ? (acc[i][j][rr] + bval[j]) : 0.f;
    }
  }
}

__global__ __launch_bounds__(256) void gemm_fb_kernel(
    const float* __restrict__ signal, const int* __restrict__ branch_idx,
    const int* __restrict__ n_valid_arr,
    const float* __restrict__ W0, const float* __restrict__ bias0,
    const float* __restrict__ W1, const float* __restrict__ bias1,
    const float* __restrict__ W2, const float* __restrict__ bias2,
    float* __restrict__ out) {
  const int et = blockIdx.x, st = blockIdx.y, b = blockIdx.z;
  const int t = threadIdx.x;
  const int s0 = st * 128, e0 = et * 128;
  const int bi = branch_idx[b];
  const int S_b = 512 >> bi;
  float* outb = out + (size_t)b * SMAX * EDIM;
  if (s0 >= S_b) {
    const float4 z = make_float4(0.f, 0.f, 0.f, 0.f);
    #pragma unroll
    for (int i = 0; i < 16; ++i) {
      int idx = t + i * 256;
      int r = idx >> 5, c = idx & 31;
      *(float4*)(outb + (size_t)(s0 + r) * EDIM + e0 + c * 4) = z;
    }
    return;
  }
  __shared__ __align__(16) ushort Ab[2 * BUFSZ];
  __shared__ __align__(16) ushort Bb[2 * BUFSZ];
  const int nv = n_valid_arr[b];
  const float* sigb = signal + (size_t)b * TLEN;
  switch (bi) {
    case 0:  gemm_fb_body<128>(sigb, W0, bias0, outb, nv, s0, e0, t, Ab, Bb); break;
    case 1:  gemm_fb_body<256>(sigb, W1, bias1, outb, nv, s0, e0, t, Ab, Bb); break;
    default: gemm_fb_body<512>(sigb, W2, bias2, outb, nv, s0, e0, t, Ab, Bb); break;
  }
}

extern "C" void kernel_launch(void* const* d_in, const int* in_sizes, int n_in,
                              void* d_out, int out_size, void* d_ws, size_t ws_size,
                              hipStream_t stream) {
  const float* signal = (const float*)d_in[0];
  const int*   mask   = (const int*)d_in[1];
  const int*   bidx   = (const int*)d_in[2];
  const float* W0 = (const float*)d_in[3];
  const float* b0 = (const float*)d_in[4];
  const float* W1 = (const float*)d_in[5];
  const float* b1 = (const float*)d_in[6];
  const float* W2 = (const float*)d_in[7];
  const float* b2 = (const float*)d_in[8];

  float* out_tokens = (float*)d_out;
  float* out_mask   = (float*)d_out + (size_t)BATCH * SMAX * EDIM;
  int*   n_valid    = (int*)d_ws;             // 128 ints
  int*   part       = (int*)d_ws + 128;       // 1024 ints

  mask_partial_kernel<<<dim3(BATCH, 8), dim3(256), 0, stream>>>(mask, part);
  mask_final_kernel<<<dim3(BATCH), dim3(256), 0, stream>>>(part, bidx, n_valid, out_mask);

  const size_t need = 8192 + (size_t)CVT_TOTAL * 2;
  if (ws_size >= need) {
    ushort* cvt_base = (ushort*)((char*)d_ws + 8192);
    ushort* sig_bf = cvt_base;
    ushort* w0_bf  = cvt_base + SIGN;
    ushort* w1_bf  = w0_bf + W0N;
    ushort* w2_bf  = w1_bf + W1N;
    cvt_kernel<<<dim3(CVT_TOTAL / 4096), dim3(256), 0, stream>>>(
        signal, W0, W1, W2, cvt_base);
    gemm_bf_kernel<<<dim3(2048), dim3(256), 0, stream>>>(
        sig_bf, bidx, n_valid, w0_bf, b0, w1_bf, b1, w2_bf, b2, out_tokens);
  } else {
    gemm_fb_kernel<<<dim3(4, 4, BATCH), dim3(256), 0, stream>>>(
        signal, bidx, n_valid, W0, b0, W1, b1, W2, b2, out_tokens);
  }
}

// Round 8
// 215.849 us; speedup vs baseline: 1.2374x; 1.2374x over previous
//
#include <hip/hip_runtime.h>
#include <hip/hip_bf16.h>

#define BATCH 128
#define TLEN  65536
#define EDIM  512
#define SMAX  512

typedef __attribute__((ext_vector_type(8))) short   bf16x8;
typedef __attribute__((ext_vector_type(4))) float   floatx4;
typedef __attribute__((ext_vector_type(8))) ushort  ushort8;

__device__ __forceinline__ ushort f2bf(float f) {
  __hip_bfloat16 h = __float2bfloat16(f);  // RNE
  return *reinterpret_cast<ushort*>(&h);
}

__device__ __forceinline__ void cvt16(ushort* dst, float4 a, float4 b,
                                      float4 c, float4 d) {
  ushort8 p0, p1;
  p0[0]=f2bf(a.x); p0[1]=f2bf(a.y); p0[2]=f2bf(a.z); p0[3]=f2bf(a.w);
  p0[4]=f2bf(b.x); p0[5]=f2bf(b.y); p0[6]=f2bf(b.z); p0[7]=f2bf(b.w);
  p1[0]=f2bf(c.x); p1[1]=f2bf(c.y); p1[2]=f2bf(c.z); p1[3]=f2bf(c.w);
  p1[4]=f2bf(d.x); p1[5]=f2bf(d.y); p1[6]=f2bf(d.z); p1[7]=f2bf(d.w);
  *(ushort8*)dst = p0; *(ushort8*)(dst + 8) = p1;
}

__device__ __forceinline__ void gl_lds16(const ushort* g, ushort* l) {
  __builtin_amdgcn_global_load_lds(
      (const __attribute__((address_space(1))) void*)g,
      (__attribute__((address_space(3))) void*)l, 16, 0, 0);
}

#define SIGN  (BATCH * TLEN)        // 8,388,608
#define W0N   (EDIM * 128)
#define W1N   (EDIM * 256)
#define W2N   (EDIM * 512)
#define CVT_TOTAL (SIGN + W0N + W1N + W2N)   // 8,847,360 = 4096*2160
#define CVT_BLOCKS (CVT_TOTAL / 4096)        // 2160
#define PREP_BLOCKS (CVT_BLOCKS + BATCH * 8) // 2160 + 1024

// ---------------------------------------------------------------------------
// Fused prep: blocks [0,2160) convert signal+weights f32->bf16 into ws;
// blocks [2160,3184) popcount 8192-int chunks of the mask into part[].
// ---------------------------------------------------------------------------
__global__ __launch_bounds__(256) void prep_kernel(
    const float* __restrict__ sig, const float* __restrict__ W0,
    const float* __restrict__ W1, const float* __restrict__ W2,
    const int* __restrict__ mask, ushort* __restrict__ dst,
    int* __restrict__ part) {
  const int blk = blockIdx.x;
  const int t = threadIdx.x;
  if (blk < CVT_BLOCKS) {
    const size_t i = ((size_t)blk * 256 + t) * 16;
    const float* src;
    if (i < SIGN)                  src = sig + i;
    else if (i < SIGN + W0N)       src = W0 + (i - SIGN);
    else if (i < SIGN + W0N + W1N) src = W1 + (i - SIGN - W0N);
    else                           src = W2 + (i - SIGN - W0N - W1N);
    const float4* s4 = (const float4*)src;
    cvt16(dst + i, s4[0], s4[1], s4[2], s4[3]);
  } else {
    const int idx = blk - CVT_BLOCKS;       // 0..1023
    const int b = idx >> 3, c = idx & 7;
    const int4* row = (const int4*)(mask + (size_t)b * TLEN + (size_t)c * 8192);
    int s = 0;
    #pragma unroll
    for (int i = 0; i < 8; ++i) {
      int4 v = row[t + i * 256];
      s += (v.x != 0) + (v.y != 0) + (v.z != 0) + (v.w != 0);
    }
    #pragma unroll
    for (int off = 32; off > 0; off >>= 1) s += __shfl_down(s, off);
    __shared__ int partial[4];
    if ((t & 63) == 0) partial[t >> 6] = s;
    __syncthreads();
    if (t == 0)
      part[idx] = partial[0] + partial[1] + partial[2] + partial[3];
  }
}

// ---------------------------------------------------------------------------
// Main MFMA GEMM (bf16 inputs from ws, global_load_lds staging, dbuf LDS).
// 128x128 tile, 4 waves (2x2 of 64x64), BK=32, 16x16x32 bf16 MFMA.
// XCD-swizzled 1-D grid: the 4 e-tile blocks sharing an A-strip get the same
// L%8 -> same XCD -> strip fetched into that XCD's L2 once.
// n_valid computed inline from part[]; (st==0,et==0) block writes mask row.
// NOTE: default launch bounds — (256,5) in R7 forced accumulator spill
// (VGPR capped at ~96 vs ~148 needed; +63MB scratch writes). Never cap below
// VGPR+AGPR need on gfx950's unified file.
// ---------------------------------------------------------------------------
template <int W>
__device__ __forceinline__ void gemm_mfma_body(
    const ushort* __restrict__ sigb, const ushort* __restrict__ Wp,
    const float* __restrict__ bp, float* __restrict__ outb,
    int nv, int s0, int e0, int t, ushort* Abuf, ushort* Bbuf) {
  constexpr int ITERS = W / 32;
  const int wave = t >> 6, lane = t & 63;
  const int lane16 = lane & 15, quad = lane >> 4;
  const int ws_ = (wave >> 1) * 64, we_ = (wave & 1) * 64;

  // staging: thread t covers flat 16B-chunks t and t+256 of each matrix;
  // chunk c -> row c>>2, swizzled k-chunk (c&3)^(row&3)
  const int c0 = t,        r0 = c0 >> 2, kc0 = (c0 & 3) ^ (r0 & 3);
  const int c1 = t + 256,  r1 = c1 >> 2, kc1 = (c1 & 3) ^ (r1 & 3);
  const ushort* ag0 = sigb + (size_t)(s0 + r0) * W + kc0 * 8;
  const ushort* ag1 = sigb + (size_t)(s0 + r1) * W + kc1 * 8;
  const ushort* bg0 = Wp + (size_t)(e0 + r0) * W + kc0 * 8;
  const ushort* bg1 = Wp + (size_t)(e0 + r1) * W + kc1 * 8;
  ushort* al0 = Abuf + wave * 512;
  ushort* al1 = Abuf + 2048 + wave * 512;
  ushort* bl0 = Bbuf + wave * 512;
  ushort* bl1 = Bbuf + 2048 + wave * 512;

  floatx4 acc[4][4];
  #pragma unroll
  for (int i = 0; i < 4; ++i)
    #pragma unroll
    for (int j = 0; j < 4; ++j) acc[i][j] = (floatx4)(0.f);

  gl_lds16(ag0, al0); gl_lds16(ag1, al1);
  gl_lds16(bg0, bl0); gl_lds16(bg1, bl1);
  __syncthreads();

  const int slotq = (quad ^ (lane16 & 3)) * 8;

  #pragma unroll
  for (int k = 0; k < ITERS; ++k) {
    if (k + 1 < ITERS) {
      const size_t ko = (size_t)(k + 1) * 32;
      const int p = ((k + 1) & 1) * 4096;
      gl_lds16(ag0 + ko, al0 + p); gl_lds16(ag1 + ko, al1 + p);
      gl_lds16(bg0 + ko, bl0 + p); gl_lds16(bg1 + ko, bl1 + p);
    }
    const ushort* A = Abuf + (k & 1) * 4096;
    const ushort* B = Bbuf + (k & 1) * 4096;
    bf16x8 af[4], bfr[4];
    #pragma unroll
    for (int i = 0; i < 4; ++i)
      af[i] = *(const bf16x8*)&A[(ws_ + i * 16 + lane16) * 32 + slotq];
    #pragma unroll
    for (int j = 0; j < 4; ++j)
      bfr[j] = *(const bf16x8*)&B[(we_ + j * 16 + lane16) * 32 + slotq];
    #pragma unroll
    for (int i = 0; i < 4; ++i)
      #pragma unroll
      for (int j = 0; j < 4; ++j)
        acc[i][j] = __builtin_amdgcn_mfma_f32_16x16x32_bf16(af[i], bfr[j], acc[i][j], 0, 0, 0);
    __syncthreads();
  }

  float bval[4];
  #pragma unroll
  for (int j = 0; j < 4; ++j) bval[j] = bp[e0 + we_ + j * 16 + lane16];
  #pragma unroll
  for (int i = 0; i < 4; ++i) {
    #pragma unroll
    for (int rr = 0; rr < 4; ++rr) {
      const int s_row = s0 + ws_ + i * 16 + quad * 4 + rr;
      const bool valid = s_row < nv;
      float* op = outb + (size_t)s_row * EDIM + e0 + we_ + lane16;
      #pragma unroll
      for (int j = 0; j < 4; ++j)
        op[j * 16] = valid ? (acc[i][j][rr] + bval[j]) : 0.f;
    }
  }
}

__global__ __launch_bounds__(256) void gemm_bf_kernel(
    const ushort* __restrict__ sigbf, const int* __restrict__ branch_idx,
    const int* __restrict__ part,
    const ushort* __restrict__ W0b, const float* __restrict__ bias0,
    const ushort* __restrict__ W1b, const float* __restrict__ bias1,
    const ushort* __restrict__ W2b, const float* __restrict__ bias2,
    float* __restrict__ out, float* __restrict__ out_mask) {
  // XCD-aware decode: slot(3b) | et(2b) | group(6b)
  const int L = blockIdx.x;
  const int slot = L & 7;
  const int et = (L >> 3) & 3;
  const int p = (L >> 5) * 8 + slot;   // 0..511
  const int st = p & 3;
  const int b = p >> 2;
  const int t = threadIdx.x;
  const int s0 = st * 128, e0 = et * 128;
  const int bi = branch_idx[b];
  const int S_b = 512 >> bi;
  float* outb = out + (size_t)b * SMAX * EDIM;

  // inline n_valid (part[] produced by prep_kernel)
  int len = 0;
  #pragma unroll
  for (int i = 0; i < 8; ++i) len += part[b * 8 + i];
  const int nv = len / (128 << bi);

  if (st == 0 && et == 0) {  // one block per sample writes the mask row
    out_mask[(size_t)b * SMAX + t]       = (t < nv)       ? 1.0f : 0.0f;
    out_mask[(size_t)b * SMAX + 256 + t] = (256 + t < nv) ? 1.0f : 0.0f;
  }

  if (s0 >= S_b) {  // pure pad tile: zero-fill (harness poisons d_out)
    const float4 z = make_float4(0.f, 0.f, 0.f, 0.f);
    #pragma unroll
    for (int i = 0; i < 16; ++i) {
      int idx = t + i * 256;
      int r = idx >> 5, c = idx & 31;
      *(float4*)(outb + (size_t)(s0 + r) * EDIM + e0 + c * 4) = z;
    }
    return;
  }

  __shared__ __align__(16) ushort Abuf[2 * 4096];  // 16 KB
  __shared__ __align__(16) ushort Bbuf[2 * 4096];  // 16 KB
  const ushort* sigb = sigbf + (size_t)b * TLEN;
  switch (bi) {
    case 0:  gemm_mfma_body<128>(sigb, W0b, bias0, outb, nv, s0, e0, t, Abuf, Bbuf); break;
    case 1:  gemm_mfma_body<256>(sigb, W1b, bias1, outb, nv, s0, e0, t, Abuf, Bbuf); break;
    default: gemm_mfma_body<512>(sigb, W2b, bias2, outb, nv, s0, e0, t, Abuf, Bbuf); break;
  }
}

// ---------------------------------------------------------------------------
// Fallback path (ws too small): standalone mask kernels + inline-cvt GEMM.
// ---------------------------------------------------------------------------
__global__ __launch_bounds__(256) void mask_partial_kernel(
    const int* __restrict__ mask, int* __restrict__ part) {
  const int b = blockIdx.x, c = blockIdx.y, t = threadIdx.x;
  const int4* row = (const int4*)(mask + (size_t)b * TLEN + (size_t)c * 8192);
  int s = 0;
  #pragma unroll
  for (int i = 0; i < 8; ++i) {
    int4 v = row[t + i * 256];
    s += (v.x != 0) + (v.y != 0) + (v.z != 0) + (v.w != 0);
  }
  #pragma unroll
  for (int off = 32; off > 0; off >>= 1) s += __shfl_down(s, off);
  __shared__ int partial[4];
  if ((t & 63) == 0) partial[t >> 6] = s;
  __syncthreads();
  if (t == 0)
    part[b * 8 + c] = partial[0] + partial[1] + partial[2] + partial[3];
}

__global__ __launch_bounds__(256) void mask_final_kernel(
    const int* __restrict__ part, const int* __restrict__ branch_idx,
    int* __restrict__ n_valid, float* __restrict__ out_mask) {
  const int b = blockIdx.x, t = threadIdx.x;
  __shared__ int nv_sh;
  if (t == 0) {
    int len = 0;
    #pragma unroll
    for (int i = 0; i < 8; ++i) len += part[b * 8 + i];
    int w = 128 << branch_idx[b];
    int nv = len / w;
    n_valid[b] = nv;
    nv_sh = nv;
  }
  __syncthreads();
  const int nv = nv_sh;
  out_mask[(size_t)b * SMAX + t]       = (t < nv)       ? 1.0f : 0.0f;
  out_mask[(size_t)b * SMAX + 256 + t] = (256 + t < nv) ? 1.0f : 0.0f;
}

#define LDS_STRIDE 40
#define BUFSZ (128 * LDS_STRIDE)

template <int W>
__device__ __forceinline__ void gemm_fb_body(
    const float* __restrict__ sigb, const float* __restrict__ Wp,
    const float* __restrict__ bp, float* __restrict__ outb,
    int nv, int s0, int e0, int t, ushort* Ab, ushort* Bb) {
  constexpr int ITERS = W / 32;
  const int wave = t >> 6, lane = t & 63;
  const int lane16 = lane & 15, quad = lane >> 4;
  const int ws_ = (wave >> 1) * 64, we_ = (wave & 1) * 64;
  const int r = t >> 1, h = t & 1;
  const float* asrc = sigb + (size_t)(s0 + r) * W + h * 16;
  const float* bsrc = Wp + (size_t)(e0 + r) * W + h * 16;
  {
    const float4* a4 = (const float4*)asrc;
    const float4* b4 = (const float4*)bsrc;
    cvt16(Ab + r * LDS_STRIDE + h * 16, a4[0], a4[1], a4[2], a4[3]);
    cvt16(Bb + r * LDS_STRIDE + h * 16, b4[0], b4[1], b4[2], b4[3]);
  }
  __syncthreads();
  floatx4 acc[4][4];
  #pragma unroll
  for (int i = 0; i < 4; ++i)
    #pragma unroll
    for (int j = 0; j < 4; ++j) acc[i][j] = (floatx4)(0.f);
  #pragma unroll
  for (int k = 0; k < ITERS; ++k) {
    const ushort* curA = Ab + (k & 1) * BUFSZ;
    const ushort* curB = Bb + (k & 1) * BUFSZ;
    float4 av0, av1, av2, av3, bv0, bv1, bv2, bv3;
    if (k + 1 < ITERS) {
      const float4* a4 = (const float4*)(asrc + (k + 1) * 32);
      const float4* b4 = (const float4*)(bsrc + (k + 1) * 32);
      av0 = a4[0]; av1 = a4[1]; av2 = a4[2]; av3 = a4[3];
      bv0 = b4[0]; bv1 = b4[1]; bv2 = b4[2]; bv3 = b4[3];
    }
    bf16x8 af[4], bfr[4];
    #pragma unroll
    for (int i = 0; i < 4; ++i)
      af[i] = *(const bf16x8*)&curA[(ws_ + i * 16 + lane16) * LDS_STRIDE + quad * 8];
    #pragma unroll
    for (int j = 0; j < 4; ++j)
      bfr[j] = *(const bf16x8*)&curB[(we_ + j * 16 + lane16) * LDS_STRIDE + quad * 8];
    #pragma unroll
    for (int i = 0; i < 4; ++i)
      #pragma unroll
      for (int j = 0; j < 4; ++j)
        acc[i][j] = __builtin_amdgcn_mfma_f32_16x16x32_bf16(af[i], bfr[j], acc[i][j], 0, 0, 0);
    if (k + 1 < ITERS) {
      cvt16(Ab + ((k + 1) & 1) * BUFSZ + r * LDS_STRIDE + h * 16, av0, av1, av2, av3);
      cvt16(Bb + ((k + 1) & 1) * BUFSZ + r * LDS_STRIDE + h * 16, bv0, bv1, bv2, bv3);
      __syncthreads();
    }
  }
  float bval[4];
  #pragma unroll
  for (int j = 0; j < 4; ++j) bval[j] = bp[e0 + we_ + j * 16 + lane16];
  #pragma unroll
  for (int i = 0; i < 4; ++i) {
    #pragma unroll
    for (int rr = 0; rr < 4; ++rr) {
      const int s_row = s0 + ws_ + i * 16 + quad * 4 + rr;
      const bool valid = s_row < nv;
      float* op = outb + (size_t)s_row * EDIM + e0 + we_ + lane16;
      #pragma unroll
      for (int j = 0; j < 4; ++j)
        op[j * 16] = valid ? (acc[i][j][rr] + bval[j]) : 0.f;
    }
  }
}

__global__ __launch_bounds__(256) void gemm_fb_kernel(
    const float* __restrict__ signal, const int* __restrict__ branch_idx,
    const int* __restrict__ n_valid_arr,
    const float* __restrict__ W0, const float* __restrict__ bias0,
    const float* __restrict__ W1, const float* __restrict__ bias1,
    const float* __restrict__ W2, const float* __restrict__ bias2,
    float* __restrict__ out) {
  const int et = blockIdx.x, st = blockIdx.y, b = blockIdx.z;
  const int t = threadIdx.x;
  const int s0 = st * 128, e0 = et * 128;
  const int bi = branch_idx[b];
  const int S_b = 512 >> bi;
  float* outb = out + (size_t)b * SMAX * EDIM;
  if (s0 >= S_b) {
    const float4 z = make_float4(0.f, 0.f, 0.f, 0.f);
    #pragma unroll
    for (int i = 0; i < 16; ++i) {
      int idx = t + i * 256;
      int r = idx >> 5, c = idx & 31;
      *(float4*)(outb + (size_t)(s0 + r) * EDIM + e0 + c * 4) = z;
    }
    return;
  }
  __shared__ __align__(16) ushort Ab[2 * BUFSZ];
  __shared__ __align__(16) ushort Bb[2 * BUFSZ];
  const int nv = n_valid_arr[b];
  const float* sigb = signal + (size_t)b * TLEN;
  switch (bi) {
    case 0:  gemm_fb_body<128>(sigb, W0, bias0, outb, nv, s0, e0, t, Ab, Bb); break;
    case 1:  gemm_fb_body<256>(sigb, W1, bias1, outb, nv, s0, e0, t, Ab, Bb); break;
    default: gemm_fb_body<512>(sigb, W2, bias2, outb, nv, s0, e0, t, Ab, Bb); break;
  }
}

extern "C" void kernel_launch(void* const* d_in, const int* in_sizes, int n_in,
                              void* d_out, int out_size, void* d_ws, size_t ws_size,
                              hipStream_t stream) {
  const float* signal = (const float*)d_in[0];
  const int*   mask   = (const int*)d_in[1];
  const int*   bidx   = (const int*)d_in[2];
  const float* W0 = (const float*)d_in[3];
  const float* b0 = (const float*)d_in[4];
  const float* W1 = (const float*)d_in[5];
  const float* b1 = (const float*)d_in[6];
  const float* W2 = (const float*)d_in[7];
  const float* b2 = (const float*)d_in[8];

  float* out_tokens = (float*)d_out;
  float* out_mask   = (float*)d_out + (size_t)BATCH * SMAX * EDIM;
  int*   n_valid    = (int*)d_ws;             // 128 ints (fallback only)
  int*   part       = (int*)d_ws + 128;       // 1024 ints

  const size_t need = 8192 + (size_t)CVT_TOTAL * 2;
  if (ws_size >= need) {
    ushort* cvt_base = (ushort*)((char*)d_ws + 8192);
    ushort* sig_bf = cvt_base;
    ushort* w0_bf  = cvt_base + SIGN;
    ushort* w1_bf  = w0_bf + W0N;
    ushort* w2_bf  = w1_bf + W1N;
    prep_kernel<<<dim3(PREP_BLOCKS), dim3(256), 0, stream>>>(
        signal, W0, W1, W2, mask, cvt_base, part);
    gemm_bf_kernel<<<dim3(2048), dim3(256), 0, stream>>>(
        sig_bf, bidx, part, w0_bf, b0, w1_bf, b1, w2_bf, b2,
        out_tokens, out_mask);
  } else {
    mask_partial_kernel<<<dim3(BATCH, 8), dim3(256), 0, stream>>>(mask, part);
    mask_final_kernel<<<dim3(BATCH), dim3(256), 0, stream>>>(part, bidx, n_valid, out_mask);
    gemm_fb_kernel<<<dim3(4, 4, BATCH), dim3(256), 0, stream>>>(
        signal, bidx, n_valid, W0, b0, W1, b1, W2, b2, out_tokens);
  }
}